// Round 5
// baseline (529.070 us; speedup 1.0000x reference)
//
#include <hip/hip_runtime.h>
#include <math.h>

#define NN 8192
#define SPARSE_WEIGHT 0.01f
#define ROWS 32      // rows per block
#define CT4 256      // float4 column-groups per block (1024 columns)

// Workspace layout (floats):
// ws[0] = sum_cos, ws[1] = sum_sin   (prep atomics, 32 blocks only)
// ws[4 .. 4+NN)        = sj[j] = alive[j]*sin(phases[j])
// ws[4+NN .. 4+2NN)    = cj[j] = alive[j]*cos(phases[j])
// ws[4+2NN ..)         = pk2[2048], pka[2048] per-block partials

__device__ __forceinline__ float wave_reduce_sum(float v) {
#pragma unroll
    for (int off = 32; off > 0; off >>= 1)
        v += __shfl_down(v, off, 64);
    return v;
}

// Kernel A: per-element sin/cos prep + global sums of cos/sin for R.
__global__ __launch_bounds__(256) void prep_kernel(
        const float* __restrict__ phases,
        const float* __restrict__ alive,
        float* __restrict__ sj,
        float* __restrict__ cj,
        float* __restrict__ acc) {
    int j = blockIdx.x * blockDim.x + threadIdx.x;
    float s = 0.f, c = 0.f;
    if (j < NN) {
        float p = phases[j];
        s = sinf(p);
        c = cosf(p);
        float a = alive[j];
        sj[j] = a * s;
        cj[j] = a * c;
    }
    float ws = wave_reduce_sum(s);
    float wc = wave_reduce_sum(c);
    __shared__ float red_s[4], red_c[4];
    int lane = threadIdx.x & 63;
    int wave = threadIdx.x >> 6;
    if (lane == 0) { red_s[wave] = ws; red_c[wave] = wc; }
    __syncthreads();
    if (threadIdx.x == 0) {
        atomicAdd(&acc[1], red_s[0] + red_s[1] + red_s[2] + red_s[3]);
        atomicAdd(&acc[0], red_c[0] + red_c[1] + red_c[2] + red_c[3]);
    }
}

// Kernel B: 2D-tiled. Block = 32 rows x 1024 cols. Each thread holds its 4
// columns' sj/cj in REGISTERS (loaded once) -> sj/cj global traffic /32.
// Only K/dist stream per row. Per-row wave-reduce -> LDS -> 8-way atomicAdd
// to dtheta[i] (distinct addresses). k2/ka per-block partials, no hot atomics.
__global__ __launch_bounds__(256, 8) void tile_kernel(
        const float* __restrict__ K,
        const float* __restrict__ dist,
        const float* __restrict__ sj,
        const float* __restrict__ cj,
        float* __restrict__ dtheta,   // out+1, pre-zeroed
        float* __restrict__ pk2,
        float* __restrict__ pka) {
    const int tid = threadIdx.x;
    const int tx = blockIdx.x;          // col tile 0..7
    const int ty = blockIdx.y;          // row group 0..255
    const int row_base = ty * ROWS;
    const int col4 = tx * CT4 + tid;    // this thread's float4-group index

    const float4* __restrict__ K4 = (const float4*)K;
    const float4* __restrict__ D4 = (const float4*)dist;

    // Per-thread column factors, loaded once.
    const float4 s4 = ((const float4*)sj)[col4];
    const float4 c4 = ((const float4*)cj)[col4];

    __shared__ float red[ROWS][4][2];   // [row][wave][t1,t2]
    __shared__ float redk[4][2];        // [wave][k2,ka]

    const int lane = tid & 63;
    const int wave = tid >> 6;

    float k2 = 0.f, ka = 0.f;
    size_t idx = (size_t)row_base * (NN / 4) + col4;

#pragma unroll 4
    for (int r = 0; r < ROWS; ++r, idx += NN / 4) {
        float4 k = K4[idx];
        float4 d = D4[idx];
        float t1, t2, km;
        km = k.x * d.x; t1  = km * s4.x; t2  = km * c4.x; k2 += k.x * k.x; ka += fabsf(k.x);
        km = k.y * d.y; t1 += km * s4.y; t2 += km * c4.y; k2 += k.y * k.y; ka += fabsf(k.y);
        km = k.z * d.z; t1 += km * s4.z; t2 += km * c4.z; k2 += k.z * k.z; ka += fabsf(k.z);
        km = k.w * d.w; t1 += km * s4.w; t2 += km * c4.w; k2 += k.w * k.w; ka += fabsf(k.w);
        t1 = wave_reduce_sum(t1);
        t2 = wave_reduce_sum(t2);
        if (lane == 0) { red[r][wave][0] = t1; red[r][wave][1] = t2; }
    }

    k2 = wave_reduce_sum(k2);
    ka = wave_reduce_sum(ka);
    if (lane == 0) { redk[wave][0] = k2; redk[wave][1] = ka; }
    __syncthreads();

    if (tid < ROWS) {
        float t1 = red[tid][0][0] + red[tid][1][0] + red[tid][2][0] + red[tid][3][0];
        float t2 = red[tid][0][1] + red[tid][1][1] + red[tid][2][1] + red[tid][3][1];
        int i = row_base + tid;
        // dtheta[i] = alive_i*(cos_i*t1 - sin_i*t2); cj/sj already carry alive_i.
        atomicAdd(&dtheta[i], cj[i] * t1 - sj[i] * t2);
    } else if (tid == ROWS) {
        int bid = ty * 8 + tx;
        pk2[bid] = redk[0][0] + redk[1][0] + redk[2][0] + redk[3][0];
        pka[bid] = redk[0][1] + redk[1][1] + redk[2][1] + redk[3][1];
    }
}

// Kernel C: reduce 2048 per-block partials + finalize scalars.
__global__ __launch_bounds__(256) void finalize_kernel(
        const float* __restrict__ acc,
        const float* __restrict__ pk2,
        const float* __restrict__ pka,
        float* __restrict__ out) {
    float k2 = 0.f, ka = 0.f;
    for (int j = threadIdx.x; j < 2048; j += 256) {
        k2 += pk2[j];
        ka += pka[j];
    }
    k2 = wave_reduce_sum(k2);
    ka = wave_reduce_sum(ka);
    __shared__ float rk2[4], rka[4];
    int lane = threadIdx.x & 63;
    int wave = threadIdx.x >> 6;
    if (lane == 0) { rk2[wave] = k2; rka[wave] = ka; }
    __syncthreads();
    if (threadIdx.x == 0) {
        float sk2 = rk2[0] + rk2[1] + rk2[2] + rk2[3];
        float ska = rka[0] + rka[1] + rka[2] + rka[3];
        float cs = acc[0] / (float)NN;
        float ss = acc[1] / (float)NN;
        float R = sqrtf(cs * cs + ss * ss);
        out[0] = R;
        out[NN + 1] = 1.0f - R + 0.01f * sqrtf(sk2) + SPARSE_WEIGHT * ska;
    }
}

extern "C" void kernel_launch(void* const* d_in, const int* in_sizes, int n_in,
                              void* d_out, int out_size, void* d_ws, size_t ws_size,
                              hipStream_t stream) {
    const float* phases = (const float*)d_in[0];
    const float* alive  = (const float*)d_in[1];
    const float* dist   = (const float*)d_in[2];
    const float* K      = (const float*)d_in[3];
    float* out = (float*)d_out;
    float* ws  = (float*)d_ws;

    float* acc = ws;                 // 4 floats (0,1 used)
    float* sj  = ws + 4;             // NN floats
    float* cj  = ws + 4 + NN;        // NN floats
    float* pk2 = ws + 4 + 2 * NN;    // 2048 floats
    float* pka = pk2 + 2048;         // 2048 floats

    (void)hipMemsetAsync(acc, 0, 4 * sizeof(float), stream);
    (void)hipMemsetAsync(out, 0, (NN + 2) * sizeof(float), stream);  // dtheta accumulated via atomics

    prep_kernel<<<NN / 256, 256, 0, stream>>>(phases, alive, sj, cj, acc);
    dim3 grid(8, NN / ROWS);  // 8 col tiles x 256 row groups = 2048 blocks = 8/CU
    tile_kernel<<<grid, 256, 0, stream>>>(K, dist, sj, cj, out + 1, pk2, pka);
    finalize_kernel<<<1, 256, 0, stream>>>(acc, pk2, pka, out);
}

// Round 6
// 523.272 us; speedup vs baseline: 1.0111x; 1.0111x over previous
//
#include <hip/hip_runtime.h>
#include <math.h>

#define NN 8192
#define SPARSE_WEIGHT 0.01f
#define ROWS 32      // rows per block
#define CT4 256      // float4 column-groups per block (1024 columns)

// Workspace layout (floats):
// ws[0] = sum_cos, ws[1] = sum_sin   (prep atomics, 32 blocks only)
// ws[4 .. 4+NN)        = sj[j] = alive[j]*sin(phases[j])
// ws[4+NN .. 4+2NN)    = cj[j] = alive[j]*cos(phases[j])
// ws[4+2NN ..)         = pk2[2048], pka[2048] per-block partials

__device__ __forceinline__ float wave_reduce_sum(float v) {
#pragma unroll
    for (int off = 32; off > 0; off >>= 1)
        v += __shfl_down(v, off, 64);
    return v;
}

// DPP-based full-wave (64-lane) sum: 6 dependent VALU steps (~2-4 cyc each)
// instead of 6 dependent ds_bpermute (~60 cyc each). Result valid in LANE 63.
template <int CTRL>
__device__ __forceinline__ float dpp_add_step(float v) {
    int t = __builtin_amdgcn_update_dpp(0, __float_as_int(v), CTRL, 0xf, 0xf, false);
    return v + __int_as_float(t);
}
__device__ __forceinline__ float dpp_wave_sum(float v) {
    v = dpp_add_step<0x111>(v);  // row_shr:1
    v = dpp_add_step<0x112>(v);  // row_shr:2
    v = dpp_add_step<0x114>(v);  // row_shr:4
    v = dpp_add_step<0x118>(v);  // row_shr:8
    v = dpp_add_step<0x142>(v);  // row_bcast:15
    v = dpp_add_step<0x143>(v);  // row_bcast:31
    return v;                    // lane 63 holds the total
}

// Kernel A: per-element sin/cos prep + global sums of cos/sin for R.
__global__ __launch_bounds__(256) void prep_kernel(
        const float* __restrict__ phases,
        const float* __restrict__ alive,
        float* __restrict__ sj,
        float* __restrict__ cj,
        float* __restrict__ acc) {
    int j = blockIdx.x * blockDim.x + threadIdx.x;
    float s = 0.f, c = 0.f;
    if (j < NN) {
        float p = phases[j];
        s = sinf(p);
        c = cosf(p);
        float a = alive[j];
        sj[j] = a * s;
        cj[j] = a * c;
    }
    float ws = wave_reduce_sum(s);
    float wc = wave_reduce_sum(c);
    __shared__ float red_s[4], red_c[4];
    int lane = threadIdx.x & 63;
    int wave = threadIdx.x >> 6;
    if (lane == 0) { red_s[wave] = ws; red_c[wave] = wc; }
    __syncthreads();
    if (threadIdx.x == 0) {
        atomicAdd(&acc[1], red_s[0] + red_s[1] + red_s[2] + red_s[3]);
        atomicAdd(&acc[0], red_c[0] + red_c[1] + red_c[2] + red_c[3]);
    }
}

// Kernel B: 2D-tiled, 32 rows x 1024 cols per block. sj/cj held in registers
// (loaded once per thread). Per-row reduce via DPP chain (VALU, no LDS pipe).
// Depth-1 row prefetch keeps K/dist loads in flight during the reduce.
__global__ __launch_bounds__(256, 8) void tile_kernel(
        const float* __restrict__ K,
        const float* __restrict__ dist,
        const float* __restrict__ sj,
        const float* __restrict__ cj,
        float* __restrict__ dtheta,   // out+1, pre-zeroed
        float* __restrict__ pk2,
        float* __restrict__ pka) {
    const int tid = threadIdx.x;
    const int tx = blockIdx.x;          // col tile 0..7
    const int ty = blockIdx.y;          // row group 0..255
    const int row_base = ty * ROWS;
    const int col4 = tx * CT4 + tid;    // this thread's float4-group index

    const float4* __restrict__ K4 = (const float4*)K;
    const float4* __restrict__ D4 = (const float4*)dist;

    const float4 s4 = ((const float4*)sj)[col4];
    const float4 c4 = ((const float4*)cj)[col4];

    __shared__ float red[ROWS][4][2];   // [row][wave][t1,t2]
    __shared__ float redk[4][2];        // [wave][k2,ka]

    const int lane = tid & 63;
    const int wave = tid >> 6;

    float k2 = 0.f, ka = 0.f;
    size_t idx = (size_t)row_base * (NN / 4) + col4;

    // Prefetch row 0.
    float4 kp = K4[idx];
    float4 dp = D4[idx];

#pragma unroll 4
    for (int r = 0; r < ROWS; ++r) {
        float4 k = kp, d = dp;
        if (r + 1 < ROWS) {             // prefetch next row while reducing this one
            idx += NN / 4;
            kp = K4[idx];
            dp = D4[idx];
        }
        float t1, t2, km;
        km = k.x * d.x; t1  = km * s4.x; t2  = km * c4.x; k2 += k.x * k.x; ka += fabsf(k.x);
        km = k.y * d.y; t1 += km * s4.y; t2 += km * c4.y; k2 += k.y * k.y; ka += fabsf(k.y);
        km = k.z * d.z; t1 += km * s4.z; t2 += km * c4.z; k2 += k.z * k.z; ka += fabsf(k.z);
        km = k.w * d.w; t1 += km * s4.w; t2 += km * c4.w; k2 += k.w * k.w; ka += fabsf(k.w);
        t1 = dpp_wave_sum(t1);
        t2 = dpp_wave_sum(t2);
        if (lane == 63) { red[r][wave][0] = t1; red[r][wave][1] = t2; }
    }

    k2 = dpp_wave_sum(k2);
    ka = dpp_wave_sum(ka);
    if (lane == 63) { redk[wave][0] = k2; redk[wave][1] = ka; }
    __syncthreads();

    if (tid < ROWS) {
        float t1 = red[tid][0][0] + red[tid][1][0] + red[tid][2][0] + red[tid][3][0];
        float t2 = red[tid][0][1] + red[tid][1][1] + red[tid][2][1] + red[tid][3][1];
        int i = row_base + tid;
        // dtheta[i] = alive_i*(cos_i*t1 - sin_i*t2); cj/sj already carry alive_i.
        atomicAdd(&dtheta[i], cj[i] * t1 - sj[i] * t2);
    } else if (tid == ROWS) {
        int bid = ty * 8 + tx;
        pk2[bid] = redk[0][0] + redk[1][0] + redk[2][0] + redk[3][0];
        pka[bid] = redk[0][1] + redk[1][1] + redk[2][1] + redk[3][1];
    }
}

// Kernel C: reduce 2048 per-block partials + finalize scalars.
__global__ __launch_bounds__(256) void finalize_kernel(
        const float* __restrict__ acc,
        const float* __restrict__ pk2,
        const float* __restrict__ pka,
        float* __restrict__ out) {
    float k2 = 0.f, ka = 0.f;
    for (int j = threadIdx.x; j < 2048; j += 256) {
        k2 += pk2[j];
        ka += pka[j];
    }
    k2 = wave_reduce_sum(k2);
    ka = wave_reduce_sum(ka);
    __shared__ float rk2[4], rka[4];
    int lane = threadIdx.x & 63;
    int wave = threadIdx.x >> 6;
    if (lane == 0) { rk2[wave] = k2; rka[wave] = ka; }
    __syncthreads();
    if (threadIdx.x == 0) {
        float sk2 = rk2[0] + rk2[1] + rk2[2] + rk2[3];
        float ska = rka[0] + rka[1] + rka[2] + rka[3];
        float cs = acc[0] / (float)NN;
        float ss = acc[1] / (float)NN;
        float R = sqrtf(cs * cs + ss * ss);
        out[0] = R;
        out[NN + 1] = 1.0f - R + 0.01f * sqrtf(sk2) + SPARSE_WEIGHT * ska;
    }
}

extern "C" void kernel_launch(void* const* d_in, const int* in_sizes, int n_in,
                              void* d_out, int out_size, void* d_ws, size_t ws_size,
                              hipStream_t stream) {
    const float* phases = (const float*)d_in[0];
    const float* alive  = (const float*)d_in[1];
    const float* dist   = (const float*)d_in[2];
    const float* K      = (const float*)d_in[3];
    float* out = (float*)d_out;
    float* ws  = (float*)d_ws;

    float* acc = ws;                 // 4 floats (0,1 used)
    float* sj  = ws + 4;             // NN floats
    float* cj  = ws + 4 + NN;        // NN floats
    float* pk2 = ws + 4 + 2 * NN;    // 2048 floats
    float* pka = pk2 + 2048;         // 2048 floats

    (void)hipMemsetAsync(acc, 0, 4 * sizeof(float), stream);
    (void)hipMemsetAsync(out, 0, (NN + 2) * sizeof(float), stream);  // dtheta accumulated via atomics

    prep_kernel<<<NN / 256, 256, 0, stream>>>(phases, alive, sj, cj, acc);
    dim3 grid(8, NN / ROWS);  // 8 col tiles x 256 row groups = 2048 blocks = 8/CU
    tile_kernel<<<grid, 256, 0, stream>>>(K, dist, sj, cj, out + 1, pk2, pka);
    finalize_kernel<<<1, 256, 0, stream>>>(acc, pk2, pka, out);
}